// Round 1
// baseline (223.939 us; speedup 1.0000x reference)
//
#include <hip/hip_runtime.h>

// HybridQLSTMCell, algebraically collapsed quantum layer.
// gate_vec = [x|hx] @ W.T + b  (4x68 matvec per row)
// z_w = cos(gate_vec_w + theta_w)
// <Z0>=z1*z2*z3, <Z1>=z0*z1, <Z2>=z0*z1*z2, <Z3>=z0*z1*z2*z3
// f,i,o = sigmoid(<Z>), g = tanh(<Z>); cx' = f*cx + i*g; hx' = o*tanh(cx')

__device__ __forceinline__ float sigm_fast(float v) {
    return 1.0f / (1.0f + __expf(-v));
}
__device__ __forceinline__ float tanh_fast(float v) {
    // 1 - 2/(e^{2v}+1): correct limits at +/-inf (no inf/inf NaN)
    return 1.0f - 2.0f / (__expf(2.0f * v) + 1.0f);
}

__global__ __launch_bounds__(256) void qlstm_kernel(
    const float* __restrict__ x,    // [B,64]
    const float* __restrict__ hx,   // [B,4]
    const float* __restrict__ cx,   // [B,4]
    const float* __restrict__ W,    // [4,68]
    const float* __restrict__ b,    // [4]
    const float* __restrict__ th_f, const float* __restrict__ th_i,
    const float* __restrict__ th_g, const float* __restrict__ th_o,
    float* __restrict__ out_h,      // [B,4]
    float* __restrict__ out_c,      // [B,4]
    int nB)
{
    __shared__ float sW[272];   // 4 rows x 68
    __shared__ float sP[20];    // b[4], th_f[4], th_i[4], th_g[4], th_o[4]
    const int t = threadIdx.x;
    for (int i = t; i < 272; i += 256) sW[i] = W[i];
    if (t < 4) {
        sP[t]      = b[t];
        sP[4 + t]  = th_f[t];
        sP[8 + t]  = th_i[t];
        sP[12 + t] = th_g[t];
        sP[16 + t] = th_o[t];
    }
    __syncthreads();

    const int idx = blockIdx.x * 256 + t;
    if (idx >= nB) return;

    // ---- 4x68 matvec: gate_vec = [x|hx] @ W.T + b ----
    const float4* xr = (const float4*)(x + (size_t)idx * 64);
    float g0 = sP[0], g1 = sP[1], g2 = sP[2], g3 = sP[3];
#pragma unroll
    for (int k = 0; k < 16; ++k) {
        const float4 v = xr[k];
        const float* w0 = &sW[0 * 68 + 4 * k];
        const float* w1 = &sW[1 * 68 + 4 * k];
        const float* w2 = &sW[2 * 68 + 4 * k];
        const float* w3 = &sW[3 * 68 + 4 * k];
        g0 += v.x * w0[0] + v.y * w0[1] + v.z * w0[2] + v.w * w0[3];
        g1 += v.x * w1[0] + v.y * w1[1] + v.z * w1[2] + v.w * w1[3];
        g2 += v.x * w2[0] + v.y * w2[1] + v.z * w2[2] + v.w * w2[3];
        g3 += v.x * w3[0] + v.y * w3[1] + v.z * w3[2] + v.w * w3[3];
    }
    const float4 h = *(const float4*)(hx + (size_t)idx * 4);
    g0 += h.x * sW[0 * 68 + 64] + h.y * sW[0 * 68 + 65] + h.z * sW[0 * 68 + 66] + h.w * sW[0 * 68 + 67];
    g1 += h.x * sW[1 * 68 + 64] + h.y * sW[1 * 68 + 65] + h.z * sW[1 * 68 + 66] + h.w * sW[1 * 68 + 67];
    g2 += h.x * sW[2 * 68 + 64] + h.y * sW[2 * 68 + 65] + h.z * sW[2 * 68 + 66] + h.w * sW[2 * 68 + 67];
    g3 += h.x * sW[3 * 68 + 64] + h.y * sW[3 * 68 + 65] + h.z * sW[3 * 68 + 66] + h.w * sW[3 * 68 + 67];

    // ---- collapsed quantum expectations per gate ----
    float e[4][4];  // [gate f,i,g,o][wire]
#pragma unroll
    for (int q = 0; q < 4; ++q) {
        const float* th = &sP[4 + 4 * q];
        const float z0 = __cosf(g0 + th[0]);
        const float z1 = __cosf(g1 + th[1]);
        const float z2 = __cosf(g2 + th[2]);
        const float z3 = __cosf(g3 + th[3]);
        const float e1 = z0 * z1;
        const float e2 = e1 * z2;
        e[q][0] = z1 * z2 * z3;
        e[q][1] = e1;
        e[q][2] = e2;
        e[q][3] = e2 * z3;
    }

    const float4 c = *(const float4*)(cx + (size_t)idx * 4);
    float cn[4], hn[4];
#pragma unroll
    for (int w = 0; w < 4; ++w) {
        const float fv = sigm_fast(e[0][w]);
        const float iv = sigm_fast(e[1][w]);
        const float gv = tanh_fast(e[2][w]);
        const float ov = sigm_fast(e[3][w]);
        const float cold = (w == 0) ? c.x : (w == 1) ? c.y : (w == 2) ? c.z : c.w;
        cn[w] = fv * cold + iv * gv;
        hn[w] = ov * tanh_fast(cn[w]);
    }
    *(float4*)(out_c + (size_t)idx * 4) = make_float4(cn[0], cn[1], cn[2], cn[3]);
    *(float4*)(out_h + (size_t)idx * 4) = make_float4(hn[0], hn[1], hn[2], hn[3]);
}

extern "C" void kernel_launch(void* const* d_in, const int* in_sizes, int n_in,
                              void* d_out, int out_size, void* d_ws, size_t ws_size,
                              hipStream_t stream) {
    const float* x    = (const float*)d_in[0];
    const float* hx   = (const float*)d_in[1];
    const float* cx   = (const float*)d_in[2];
    const float* W    = (const float*)d_in[3];
    const float* b    = (const float*)d_in[4];
    const float* th_f = (const float*)d_in[5];
    const float* th_i = (const float*)d_in[6];
    const float* th_g = (const float*)d_in[7];
    const float* th_o = (const float*)d_in[8];

    const int nB = in_sizes[0] / 64;          // 524288
    float* out_h = (float*)d_out;             // [B,4]
    float* out_c = out_h + (size_t)nB * 4;    // [B,4]

    const int blocks = (nB + 255) / 256;      // 2048
    hipLaunchKernelGGL(qlstm_kernel, dim3(blocks), dim3(256), 0, stream,
                       x, hx, cx, W, b, th_f, th_i, th_g, th_o, out_h, out_c, nB);
}